// Round 16
// baseline (699.784 us; speedup 1.0000x reference)
//
#include <hip/hip_runtime.h>

#define D 128
#define EDIMC 16
#define GCAP 64

typedef __attribute__((ext_vector_type(8))) short short8v;
typedef __attribute__((ext_vector_type(4))) float f32x4;
typedef __attribute__((ext_vector_type(2))) float f32x2;
typedef __attribute__((ext_vector_type(2))) _Float16 h16x2;

__device__ __forceinline__ float asf(unsigned u){ union{unsigned u; float f;} v; v.u = u; return v.f; }
__device__ __forceinline__ unsigned asu(float f){ union{float f; unsigned u;} v; v.f = f; return v.u; }
__device__ __forceinline__ unsigned short f2bf(float f){
    unsigned u = asu(f);
    unsigned r = (u + 0x7fffu + ((u >> 16) & 1u)) >> 16;   // RNE
    return (unsigned short)r;
}
__device__ __forceinline__ unsigned packbf(float lo, float hi){
    return (unsigned)f2bf(lo) | ((unsigned)f2bf(hi) << 16);
}
__device__ __forceinline__ unsigned packh(float a, float b){
    union{ h16x2 h; unsigned u; } v;
    v.h = (h16x2){(_Float16)a, (_Float16)b};
    return v.u;
}
__device__ __forceinline__ h16x2 ash2(unsigned u){ union{unsigned u; h16x2 h;} v; v.u = u; return v.h; }

// ================= fused prep =================
__global__ __launch_bounds__(256) void prep_all(
    const int* __restrict__ row, const int* __restrict__ col,
    const int* __restrict__ asrc_in, const int* __restrict__ adst,
    int E, int N, int gE, int gX, int L,
    const float* __restrict__ eattr, const float* __restrict__ x,
    const float* __restrict__ gW, const float* __restrict__ Wv,
    const float* __restrict__ Wqk, const float* __restrict__ Wout,
    const float* __restrict__ gWe, const float* __restrict__ bse,
    const float* __restrict__ Wse,
    int* __restrict__ cr, int* __restrict__ curg, int* __restrict__ curd,
    int* __restrict__ gslot, int* __restrict__ asrcS, unsigned* __restrict__ eattrh,
    unsigned* __restrict__ xbf, unsigned* __restrict__ xc,
    unsigned short* __restrict__ gWt, unsigned short* __restrict__ Wvt,
    unsigned short* __restrict__ Woutt, unsigned* __restrict__ wpk,
    float* __restrict__ WseWqk, float* __restrict__ bconst)
{
    int b = blockIdx.x, tid = threadIdx.x;
    if(b < gE){
        int e = b*256 + tid;
        if(e >= E) return;
        const float4* s4 = (const float4*)(eattr + (size_t)e*EDIMC);
        float4 a = s4[0], bb = s4[1], cc2 = s4[2], d = s4[3];
        unsigned* dst8 = eattrh + (size_t)e*8;
        dst8[0] = packh(a.x, a.y);    dst8[1] = packh(a.z, a.w);
        dst8[2] = packh(bb.x, bb.y);  dst8[3] = packh(bb.z, bb.w);
        dst8[4] = packh(cc2.x, cc2.y);dst8[5] = packh(cc2.z, cc2.w);
        dst8[6] = packh(d.x, d.y);    dst8[7] = packh(d.z, d.w);
        int r = row[e], c = col[e];
        atomicAdd(&cr[r], 1);
        int pg = atomicAdd(&curg[c], 1);
        if(pg < GCAP) gslot[c*GCAP + pg] = e;          // edge id only (4B)
        int s2 = asrc_in[e], d2 = adst[e];
        int pd = atomicAdd(&curd[d2], 1);
        if(pd < GCAP) asrcS[d2*GCAP + pd] = s2;
    } else if(b < gE + gX){
        int idx = (b - gE)*256 + tid;
        if(idx >= N*64) return;
        int i = idx >> 6, c2 = idx & 63;
        float a = x[(size_t)i*128 + c2*2], bb = x[(size_t)i*128 + c2*2 + 1];
        unsigned p = packbf(a, bb);
        xbf[idx] = p;
        xc[(size_t)i*256 + c2] = p;
    } else {
        int wb = b - gE - gX;
        int j = tid;
        if(wb < 384){
            int l = wb >> 7, k = wb & 127;
            if(j < 128) gWt[(size_t)l*16384 + (size_t)j*128 + k] = f2bf(gW[(size_t)l*16384 + (size_t)k*128 + j]);
        } else if(wb < 512){
            int k = wb - 384;
            if(j < 128) Wvt[(size_t)j*128 + k] = f2bf(Wv[(size_t)k*128 + j]);
        } else if(wb < 640){
            int k = wb - 512;
            if(j < 128) Woutt[(size_t)j*128 + k] = f2bf(Wout[(size_t)k*128 + j]);
        } else if(wb < 664){
            int t = wb - 640; int l = t >> 3, kk = t & 7;
            if(j < 128){
                const float* W = gWe + (size_t)l*EDIMC*D;
                wpk[(size_t)l*1024 + kk*128 + j] = packh(W[(size_t)(2*kk)*D + j], W[(size_t)(2*kk+1)*D + j]);
            }
        } else if(wb < 1176){
            int k = wb - 664;   // 0..511
            float acc = 0.f;
            #pragma unroll 4
            for(int c = 0; c < 128; c++)
                acc += Wse[(size_t)k*128 + c] * Wqk[(size_t)c*256 + j];
            WseWqk[(size_t)k*256 + j] = acc;
        } else {
            float acc = 0.f;
            #pragma unroll 4
            for(int c = 0; c < 128; c++)
                acc += bse[c] * Wqk[(size_t)c*256 + j];
            bconst[j] = acc;
        }
    }
}

__global__ void deg_fin2(const int* __restrict__ cr, float* __restrict__ deg,
                         float* __restrict__ dis, int N){
    int i = blockIdx.x*blockDim.x + threadIdx.x;
    if(i < N){ float d = (float)cr[i] + 1.0f; deg[i] = d; dis[i] = rsqrtf(d); }
}

// ---------------- LDS-tiled bf16 MFMA GEMM ----------------
template<int OUT>
__global__ __launch_bounds__(256) void gemm_lds(
    const unsigned short* __restrict__ A, const unsigned short* __restrict__ Bt,
    const float* __restrict__ bias, void* __restrict__ Cout,
    int M, int K, int Nc)
{
    __shared__ unsigned short As[128*64];
    __shared__ unsigned short Bs[128*64];
    int tid = threadIdx.x;
    int lane = tid & 63;
    int wid = tid >> 6;
    int bm = blockIdx.y*128, bn = blockIdx.x*128;
    int wr = (wid >> 1)*64, wc = (wid & 1)*64;
    int lr = lane & 15, kg = lane >> 4;
    f32x4 acc[4][4];
    #pragma unroll
    for(int i = 0; i < 4; i++)
        #pragma unroll
        for(int j = 0; j < 4; j++) acc[i][j] = (f32x4){0.f,0.f,0.f,0.f};

    for(int k0 = 0; k0 < K; k0 += 64){
        #pragma unroll
        for(int i = 0; i < 4; i++){
            int q = tid + 256*i;
            int row = q >> 3, c8 = (q & 7)*8;
            int ar = bm + row; if(ar >= M) ar = M - 1;
            *(short8v*)&As[row*64 + c8] = *(const short8v*)&A[(size_t)ar*K + k0 + c8];
            *(short8v*)&Bs[row*64 + c8] = *(const short8v*)&Bt[(size_t)(bn + row)*K + k0 + c8];
        }
        __syncthreads();
        #pragma unroll
        for(int kk = 0; kk < 2; kk++){
            short8v a[4], b[4];
            #pragma unroll
            for(int i = 0; i < 4; i++)
                a[i] = *(const short8v*)&As[(wr + i*16 + lr)*64 + kk*32 + kg*8];
            #pragma unroll
            for(int j = 0; j < 4; j++)
                b[j] = *(const short8v*)&Bs[(wc + j*16 + lr)*64 + kk*32 + kg*8];
            #pragma unroll
            for(int i = 0; i < 4; i++)
                #pragma unroll
                for(int j = 0; j < 4; j++)
                    acc[i][j] = __builtin_amdgcn_mfma_f32_16x16x32_bf16(a[i], b[j], acc[i][j], 0, 0, 0);
        }
        __syncthreads();
    }
    #pragma unroll
    for(int j = 0; j < 4; j++){
        int col = bn + wc + j*16 + lr;
        float bs = bias ? bias[col] : 0.f;
        #pragma unroll
        for(int i = 0; i < 4; i++){
            int rbase = bm + wr + i*16 + kg*4;
            #pragma unroll
            for(int r = 0; r < 4; r++){
                int rw = rbase + r;
                if(rw < M){
                    float val = acc[i][j][r] + bs;
                    if(OUT == 1)
                        ((unsigned short*)Cout)[(size_t)rw*Nc + col] = f2bf(val);
                    else if(OUT == 2)
                        ((_Float16*)Cout)[(size_t)rw*Nc + col] = (_Float16)val;
                    else
                        ((float*)Cout)[(size_t)rw*Nc + col] = val;
                }
            }
        }
    }
}

// ---------------- GCN gather v13: wave-per-node, edge-id slots, f16 dot2 ----------------
__device__ __forceinline__ void edge_acc5(
    uint4 ea0, uint4 ea1, unsigned hu, float nm,
    const unsigned* __restrict__ w0, const unsigned* __restrict__ w1,
    float be0, float be1, float& a0, float& a1)
{
    float ev0 = be0, ev1 = be1;
    unsigned ea[8] = {ea0.x, ea0.y, ea0.z, ea0.w, ea1.x, ea1.y, ea1.z, ea1.w};
    #pragma unroll
    for(int kk = 0; kk < 8; kk++){
        ev0 = __builtin_amdgcn_fdot2(ash2(ea[kk]), ash2(w0[kk]), ev0, false);
        ev1 = __builtin_amdgcn_fdot2(ash2(ea[kk]), ash2(w1[kk]), ev1, false);
    }
    float sx = fmaxf(asf(hu << 16) + ev0, 0.f);
    float sy = fmaxf(asf(hu & 0xffff0000u) + ev1, 0.f);
    a0 += nm*sx; a1 += nm*sy;
}

__global__ __launch_bounds__(256) void gcn_gather_v13(
    const unsigned* __restrict__ hlin, const int* __restrict__ curg,
    const int* __restrict__ gslot, const int* __restrict__ erow,
    const unsigned* __restrict__ eattrh,
    const float* __restrict__ dis, const unsigned* __restrict__ wpk_l,
    const float* __restrict__ be, const float* __restrict__ root,
    const float* __restrict__ deg,
    unsigned* __restrict__ xc, unsigned* __restrict__ hcur, int blk, int N)
{
    int lane = threadIdx.x & 63;
    int node = __builtin_amdgcn_readfirstlane((int)((blockIdx.x*blockDim.x + threadIdx.x) >> 6));
    if(node >= N) return;
    unsigned w0[8], w1[8];
    const uint2* wp2 = (const uint2*)wpk_l;
    #pragma unroll
    for(int kk = 0; kk < 8; kk++){
        uint2 t = wp2[(size_t)kk*64 + lane];
        w0[kk] = t.x; w1[kk] = t.y;
    }
    f32x2 be2 = ((const f32x2*)be)[lane];
    f32x2 rt2 = ((const f32x2*)root)[lane];
    float disn = dis[node];
    int s0 = node*GCAP;
    int s1 = s0 + min(curg[node], GCAP);
    float a0 = 0.f, a1 = 0.f;
    int s = s0;
    for(; s + 4 <= s1; s += 4){
        int e0 = gslot[s+0], e1 = gslot[s+1], e2 = gslot[s+2], e3 = gslot[s+3];
        int r0 = erow[e0], r1 = erow[e1], r2 = erow[e2], r3 = erow[e3];
        float d0 = dis[r0], d1 = dis[r1], d2 = dis[r2], d3 = dis[r3];
        unsigned h0 = hlin[(size_t)r0*64 + lane];
        unsigned h1 = hlin[(size_t)r1*64 + lane];
        unsigned h2 = hlin[(size_t)r2*64 + lane];
        unsigned h3 = hlin[(size_t)r3*64 + lane];
        uint4 e00 = *(const uint4*)(eattrh + (size_t)e0*8);
        uint4 e01 = *(const uint4*)(eattrh + (size_t)e0*8 + 4);
        uint4 e10 = *(const uint4*)(eattrh + (size_t)e1*8);
        uint4 e11 = *(const uint4*)(eattrh + (size_t)e1*8 + 4);
        uint4 e20 = *(const uint4*)(eattrh + (size_t)e2*8);
        uint4 e21 = *(const uint4*)(eattrh + (size_t)e2*8 + 4);
        uint4 e30 = *(const uint4*)(eattrh + (size_t)e3*8);
        uint4 e31 = *(const uint4*)(eattrh + (size_t)e3*8 + 4);
        edge_acc5(e00, e01, h0, d0*disn, w0, w1, be2.x, be2.y, a0, a1);
        edge_acc5(e10, e11, h1, d1*disn, w0, w1, be2.x, be2.y, a0, a1);
        edge_acc5(e20, e21, h2, d2*disn, w0, w1, be2.x, be2.y, a0, a1);
        edge_acc5(e30, e31, h3, d3*disn, w0, w1, be2.x, be2.y, a0, a1);
    }
    for(; s < s1; s++){
        int e0 = gslot[s];
        int r0 = erow[e0];
        float d0 = dis[r0];
        unsigned h0 = hlin[(size_t)r0*64 + lane];
        uint4 e00 = *(const uint4*)(eattrh + (size_t)e0*8);
        uint4 e01 = *(const uint4*)(eattrh + (size_t)e0*8 + 4);
        edge_acc5(e00, e01, h0, d0*disn, w0, w1, be2.x, be2.y, a0, a1);
    }
    unsigned hlu = hlin[(size_t)node*64 + lane];
    float hlx = asf(hlu << 16), hly = asf(hlu & 0xffff0000u);
    float dinv = 1.f/deg[node];
    float v0 = fmaxf(a0 + fmaxf(hlx + rt2.x, 0.f)*dinv, 0.f);
    float v1 = fmaxf(a1 + fmaxf(hly + rt2.y, 0.f)*dinv, 0.f);
    unsigned p = packbf(v0, v1);
    hcur[(size_t)node*64 + lane] = p;
    xc[(size_t)node*256 + (size_t)blk*64 + lane] = p;
}

// ---------------- BN statistics from bf16 xc ----------------
__global__ __launch_bounds__(256) void bn_stats_bf(
    const unsigned* __restrict__ xc, int N, float* __restrict__ stats)
{
    int c0 = threadIdx.x;
    int rows_per = (N + gridDim.x - 1)/gridDim.x;
    int r0 = blockIdx.x*rows_per, r1 = min(N, r0 + rows_per);
    float s0=0, q0=0, s1=0, q1=0;
    for(int r = r0; r < r1; r++){
        unsigned u = xc[(size_t)r*256 + c0];
        float a = asf(u << 16), b = asf(u & 0xffff0000u);
        s0 += a; q0 += a*a; s1 += b; q1 += b*b;
    }
    atomicAdd(&stats[2*c0+0], s0);  atomicAdd(&stats[512 + 2*c0+0], q0);
    atomicAdd(&stats[2*c0+1], s1);  atomicAdd(&stats[512 + 2*c0+1], q1);
}

// ---------------- fold ----------------
__global__ void fold_all(const float* __restrict__ gamma, const float* __restrict__ beta,
                         const float* __restrict__ stats, float Ninv,
                         const float* __restrict__ WseWqk, const float* __restrict__ bconst,
                         unsigned short* __restrict__ Wqkft, float* __restrict__ bqkf)
{
    int b = blockIdx.x, t = threadIdx.x;
    if(b < 256){
        int j = b;
        #pragma unroll
        for(int half = 0; half < 2; half++){
            int k = t + half*256;
            float mu  = stats[k]*Ninv;
            float var = stats[512+k]*Ninv - mu*mu;
            float sc  = gamma[k]*rsqrtf(var + 1e-5f);
            Wqkft[(size_t)j*512 + k] = f2bf(sc * WseWqk[(size_t)k*256 + j]);
        }
    } else {
        int j = t;
        float acc = bconst[j];
        for(int k = 0; k < 512; k++){
            float mu  = stats[k]*Ninv;
            float var = stats[512+k]*Ninv - mu*mu;
            float sc  = gamma[k]*rsqrtf(var + 1e-5f);
            float sh  = beta[k] - mu*sc;
            acc += sh*WseWqk[(size_t)k*256 + j];
        }
        bqkf[j] = acc;
    }
}

// ---------------- fused attention v8: slot buckets, f16 dot2, chunk-max softmax ----------------
__global__ __launch_bounds__(256) void attn_fused_v8(
    const unsigned* __restrict__ qk, const unsigned* __restrict__ v,
    const int* __restrict__ curd, const int* __restrict__ asrcS,
    unsigned* __restrict__ out, int N)
{
    int lane = threadIdx.x & 63;
    int node = __builtin_amdgcn_readfirstlane((int)((blockIdx.x*blockDim.x + threadIdx.x) >> 6));
    if(node >= N) return;
    int cnt = min(curd[node], GCAP);
    int s0 = node*GCAP, s1 = s0 + cnt;
    float o0 = 0.f, o1 = 0.f;
    if(cnt > 0){
        h16x2 qi2 = ash2(qk[(size_t)node*128 + 64 + lane]);
        float m = -INFINITY, ssum = 0.f, a0 = 0.f, a1 = 0.f;
        int s = s0;
        for(; s + 4 <= s1; s += 4){
            int sr0 = asrcS[s+0], sr1 = asrcS[s+1], sr2 = asrcS[s+2], sr3 = asrcS[s+3];
            unsigned qj[4], vv[4];
            qj[0] = qk[(size_t)sr0*128 + lane];  vv[0] = v[(size_t)sr0*64 + lane];
            qj[1] = qk[(size_t)sr1*128 + lane];  vv[1] = v[(size_t)sr1*64 + lane];
            qj[2] = qk[(size_t)sr2*128 + lane];  vv[2] = v[(size_t)sr2*64 + lane];
            qj[3] = qk[(size_t)sr3*128 + lane];  vv[3] = v[(size_t)sr3*64 + lane];
            float l[4];
            #pragma unroll
            for(int j = 0; j < 4; j++){
                float p = __builtin_amdgcn_fdot2(qi2, ash2(qj[j]), 0.f, false);
                p += __shfl_xor(p, 1);
                p += __shfl_xor(p, 2);
                p += __shfl_xor(p, 4);
                l[j] = p*0.25f;
            }
            float mc = fmaxf(fmaxf(fmaxf(l[0], l[1]), fmaxf(l[2], l[3])), m);
            float sc = __expf(m - mc);
            float p0 = __expf(l[0] - mc), p1 = __expf(l[1] - mc);
            float p2 = __expf(l[2] - mc), p3 = __expf(l[3] - mc);
            h16x2 v0 = ash2(vv[0]), v1 = ash2(vv[1]), v2 = ash2(vv[2]), v3 = ash2(vv[3]);
            ssum = ssum*sc + (p0 + p1 + p2 + p3);
            a0 = a0*sc + p0*(float)v0.x + p1*(float)v1.x + p2*(float)v2.x + p3*(float)v3.x;
            a1 = a1*sc + p0*(float)v0.y + p1*(float)v1.y + p2*(float)v2.y + p3*(float)v3.y;
            m = mc;
        }
        for(; s < s1; s++){
            int srx = asrcS[s];
            h16x2 qj2 = ash2(qk[(size_t)srx*128 + lane]);
            h16x2 v2  = ash2(v [(size_t)srx*64  + lane]);
            float p = __builtin_amdgcn_fdot2(qi2, qj2, 0.f, false);
            p += __shfl_xor(p, 1);
            p += __shfl_xor(p, 2);
            p += __shfl_xor(p, 4);
            float l = p*0.25f;
            float mn = fmaxf(m, l);
            float sc = __expf(m - mn);
            float pe = __expf(l - mn);
            ssum = ssum*sc + pe;
            a0 = a0*sc + pe*(float)v2.x;
            a1 = a1*sc + pe*(float)v2.y;
            m = mn;
        }
        float inv = 1.f/ssum;
        o0 = a0*inv; o1 = a1*inv;
    }
    out[(size_t)node*64 + lane] = packbf(o0, o1);
}

extern "C" void kernel_launch(void* const* d_in, const int* in_sizes, int n_in,
                              void* d_out, int out_size, void* d_ws, size_t ws_size,
                              hipStream_t stream)
{
    const float* x     = (const float*)d_in[0];
    const int*   ei    = (const int*)  d_in[1];
    const float* eattr = (const float*)d_in[2];
    const int*   dei   = (const int*)  d_in[3];
    const float* Wv    = (const float*)d_in[4];
    const float* Wqk   = (const float*)d_in[5];
    const float* gW    = (const float*)d_in[6];
    const float* gb    = (const float*)d_in[7];
    const float* groot = (const float*)d_in[8];
    const float* gWe   = (const float*)d_in[9];
    const float* gbe   = (const float*)d_in[10];
    const float* gamma = (const float*)d_in[11];
    const float* beta  = (const float*)d_in[12];
    const float* Wse   = (const float*)d_in[13];
    const float* bse   = (const float*)d_in[14];
    const float* Wout  = (const float*)d_in[15];
    const float* bout  = (const float*)d_in[16];

    const int N = in_sizes[0]/D;
    const int E = in_sizes[1]/2;
    const int L = in_sizes[7]/D;

    float* ws = (float*)d_ws;
    size_t o = 0;
    auto alloc = [&](size_t n){ size_t r = o; o += (n + 63) & ~(size_t)63; return r; };
    size_t f_deg   = alloc((size_t)N);
    size_t f_dis   = alloc((size_t)N);
    size_t f_hlin  = alloc((size_t)N*64);
    size_t f_hcur  = alloc((size_t)N*64);
    size_t f_xbf   = alloc((size_t)N*64);
    size_t f_xc    = alloc((size_t)N*256);
    size_t f_st    = alloc(1024);
    size_t f_cnt   = alloc((size_t)N*3);
    size_t f_gslot = alloc((size_t)N*GCAP);   // int (edge ids)
    size_t f_asrc  = alloc((size_t)N*GCAP);
    size_t f_eah   = alloc((size_t)E*8);
    size_t f_wgt   = alloc(40960 + 64);
    size_t f_wpk   = alloc(3*1024);
    size_t f_wsq   = alloc(512*256);
    size_t f_bcn   = alloc(256);
    size_t f_wqf   = alloc(65536);
    size_t f_bqf   = alloc(256);
    size_t f_qk    = alloc((size_t)N*128);
    size_t f_vb    = alloc((size_t)N*64);
    size_t f_aout  = alloc((size_t)N*64);
    (void)ws_size;

    float* deg  = ws + f_deg;   float* dis  = ws + f_dis;
    unsigned* hlin = (unsigned*)(ws + f_hlin);
    unsigned* hcur = (unsigned*)(ws + f_hcur);
    unsigned* xbf  = (unsigned*)(ws + f_xbf);
    unsigned* xc   = (unsigned*)(ws + f_xc);
    float* stats = ws + f_st;
    int* cnts = (int*)(ws + f_cnt);
    int* cr = cnts, *curg = cnts + N, *curd = cnts + 2*N;
    int* gslot = (int*)(ws + f_gslot);
    int* asrcS = (int*)(ws + f_asrc);
    unsigned* eattrh = (unsigned*)(ws + f_eah);
    unsigned short* wbase = (unsigned short*)(ws + f_wgt);
    unsigned short* gWt   = wbase;
    unsigned short* Wvt   = gWt + 3*128*128;
    unsigned short* Woutt = Wvt + 128*128;
    unsigned* wpk = (unsigned*)(ws + f_wpk);
    float* WseWqk = ws + f_wsq;
    float* bconst = ws + f_bcn;
    unsigned short* Wqkft = (unsigned short*)(ws + f_wqf);
    float* bqkf = ws + f_bqf;
    unsigned* qk   = (unsigned*)(ws + f_qk);
    unsigned* vbuf = (unsigned*)(ws + f_vb);
    unsigned* aout = (unsigned*)(ws + f_aout);

    const int* e_row = ei;        const int* e_col = ei + E;
    const int* a_src = dei;       const int* a_dst = dei + E;

    dim3 blk256(256);
    int gE = (E+255)/256, gN = (N+255)/256;
    int gNode = ((size_t)N*64 + 255)/256;
    int gX = gNode;
    int gM128 = (N+127)/128;

    // ---- fused prep ----
    hipMemsetAsync(cnts, 0, (size_t)N*3*sizeof(int), stream);
    prep_all<<<gE + gX + 1177, blk256, 0, stream>>>(
        e_row, e_col, a_src, a_dst, E, N, gE, gX, L,
        eattr, x, gW, Wv, Wqk, Wout, gWe, bse, Wse,
        cr, curg, curd, gslot, asrcS, eattrh,
        xbf, xc, gWt, Wvt, Woutt, wpk, WseWqk, bconst);
    deg_fin2<<<gN, blk256, 0, stream>>>(cr, deg, dis, N);

    // ---- GCN layers ----
    const unsigned* hin = xbf;
    for(int l = 0; l < L; l++){
        dim3 g(1, gM128);
        gemm_lds<1><<<g, blk256, 0, stream>>>((const unsigned short*)hin, gWt + (size_t)l*D*D,
                                              gb + (size_t)l*D, hlin, N, 128, 128);
        gcn_gather_v13<<<gNode, blk256, 0, stream>>>(hlin, curg, gslot, e_row, eattrh, dis,
                                                     wpk + (size_t)l*1024, gbe + (size_t)l*D,
                                                     groot + (size_t)l*D, deg, xc, hcur, l+1, N);
        hin = hcur;
    }

    // ---- BN stats + fold ----
    hipMemsetAsync(stats, 0, 1024*sizeof(float), stream);
    bn_stats_bf<<<1024, blk256, 0, stream>>>(xc, N, stats);
    float Ninv = 1.0f/(float)N;
    fold_all<<<257, blk256, 0, stream>>>(gamma, beta, stats, Ninv, WseWqk, bconst, Wqkft, bqkf);

    // ---- projections ----
    {   dim3 g(1, gM128);   // v = x @ Wv (f16 out)
        gemm_lds<2><<<g, blk256, 0, stream>>>((const unsigned short*)xbf, Wvt, nullptr, vbuf, N, 128, 128);
    }
    {   dim3 g(2, gM128);   // qk = xc @ Wqkft + bqkf (f16 out), K=512
        gemm_lds<2><<<g, blk256, 0, stream>>>((const unsigned short*)xc, Wqkft, bqkf, qk, N, 512, 256);
    }

    // ---- fused attention ----
    attn_fused_v8<<<gNode, blk256, 0, stream>>>(qk, vbuf, curd, asrcS, aout, N);

    // ---- out = attn_out @ Wout + bout (fp32 out) ----
    {   dim3 g(1, gM128);
        gemm_lds<0><<<g, blk256, 0, stream>>>((const unsigned short*)aout, Woutt, bout, (float*)d_out, N, 128, 128);
    }
}

// Round 17
// 617.640 us; speedup vs baseline: 1.1330x; 1.1330x over previous
//
#include <hip/hip_runtime.h>

#define D 128
#define EDIMC 16
#define GCAP 64

typedef __attribute__((ext_vector_type(8))) short short8v;
typedef __attribute__((ext_vector_type(4))) float f32x4;
typedef __attribute__((ext_vector_type(2))) float f32x2;
typedef __attribute__((ext_vector_type(2))) _Float16 h16x2;

__device__ __forceinline__ float asf(unsigned u){ union{unsigned u; float f;} v; v.u = u; return v.f; }
__device__ __forceinline__ unsigned asu(float f){ union{float f; unsigned u;} v; v.f = f; return v.u; }
__device__ __forceinline__ unsigned short f2bf(float f){
    unsigned u = asu(f);
    unsigned r = (u + 0x7fffu + ((u >> 16) & 1u)) >> 16;   // RNE
    return (unsigned short)r;
}
__device__ __forceinline__ unsigned packbf(float lo, float hi){
    return (unsigned)f2bf(lo) | ((unsigned)f2bf(hi) << 16);
}
__device__ __forceinline__ unsigned packh(float a, float b){
    union{ h16x2 h; unsigned u; } v;
    v.h = (h16x2){(_Float16)a, (_Float16)b};
    return v.u;
}
__device__ __forceinline__ h16x2 ash2(unsigned u){ union{unsigned u; h16x2 h;} v; v.u = u; return v.h; }

// ================= fused prep =================
__global__ __launch_bounds__(256) void prep_all(
    const int* __restrict__ row, const int* __restrict__ col,
    const int* __restrict__ asrc_in, const int* __restrict__ adst,
    int E, int N, int gE, int gX, int L,
    const float* __restrict__ eattr, const float* __restrict__ x,
    const float* __restrict__ gW, const float* __restrict__ Wv,
    const float* __restrict__ Wqk, const float* __restrict__ Wout,
    const float* __restrict__ gWe, const float* __restrict__ bse,
    const float* __restrict__ Wse,
    int* __restrict__ cr, int* __restrict__ curg, int* __restrict__ curd,
    int2* __restrict__ gslot, int* __restrict__ asrcS, unsigned* __restrict__ eattrh,
    unsigned* __restrict__ xbf, unsigned* __restrict__ xc,
    unsigned short* __restrict__ gWt, unsigned short* __restrict__ Wvt,
    unsigned short* __restrict__ Woutt, unsigned* __restrict__ wpk,
    float* __restrict__ WseWqk, float* __restrict__ bconst)
{
    int b = blockIdx.x, tid = threadIdx.x;
    if(b < gE){
        int e = b*256 + tid;
        if(e >= E) return;
        const float4* s4 = (const float4*)(eattr + (size_t)e*EDIMC);
        float4 a = s4[0], bb = s4[1], cc2 = s4[2], d = s4[3];
        unsigned* dst8 = eattrh + (size_t)e*8;
        dst8[0] = packh(a.x, a.y);    dst8[1] = packh(a.z, a.w);
        dst8[2] = packh(bb.x, bb.y);  dst8[3] = packh(bb.z, bb.w);
        dst8[4] = packh(cc2.x, cc2.y);dst8[5] = packh(cc2.z, cc2.w);
        dst8[6] = packh(d.x, d.y);    dst8[7] = packh(d.z, d.w);
        int r = row[e], c = col[e];
        atomicAdd(&cr[r], 1);
        int pg = atomicAdd(&curg[c], 1);
        if(pg < GCAP) gslot[c*GCAP + pg] = make_int2(r, e);
        int s2 = asrc_in[e], d2 = adst[e];
        int pd = atomicAdd(&curd[d2], 1);
        if(pd < GCAP) asrcS[d2*GCAP + pd] = s2;
    } else if(b < gE + gX){
        int idx = (b - gE)*256 + tid;
        if(idx >= N*64) return;
        int i = idx >> 6, c2 = idx & 63;
        float a = x[(size_t)i*128 + c2*2], bb = x[(size_t)i*128 + c2*2 + 1];
        unsigned p = packbf(a, bb);
        xbf[idx] = p;
        xc[(size_t)i*256 + c2] = p;
    } else {
        int wb = b - gE - gX;
        int j = tid;
        if(wb < 384){
            int l = wb >> 7, k = wb & 127;
            if(j < 128) gWt[(size_t)l*16384 + (size_t)j*128 + k] = f2bf(gW[(size_t)l*16384 + (size_t)k*128 + j]);
        } else if(wb < 512){
            int k = wb - 384;
            if(j < 128) Wvt[(size_t)j*128 + k] = f2bf(Wv[(size_t)k*128 + j]);
        } else if(wb < 640){
            int k = wb - 512;
            if(j < 128) Woutt[(size_t)j*128 + k] = f2bf(Wout[(size_t)k*128 + j]);
        } else if(wb < 664){
            int t = wb - 640; int l = t >> 3, kk = t & 7;
            if(j < 128){
                const float* W = gWe + (size_t)l*EDIMC*D;
                wpk[(size_t)l*1024 + kk*128 + j] = packh(W[(size_t)(2*kk)*D + j], W[(size_t)(2*kk+1)*D + j]);
            }
        } else if(wb < 1176){
            int k = wb - 664;   // 0..511
            float acc = 0.f;
            #pragma unroll 4
            for(int c = 0; c < 128; c++)
                acc += Wse[(size_t)k*128 + c] * Wqk[(size_t)c*256 + j];
            WseWqk[(size_t)k*256 + j] = acc;
        } else {
            float acc = 0.f;
            #pragma unroll 4
            for(int c = 0; c < 128; c++)
                acc += bse[c] * Wqk[(size_t)c*256 + j];
            bconst[j] = acc;
        }
    }
}

__global__ void deg_fin2(const int* __restrict__ cr, float* __restrict__ deg,
                         float* __restrict__ dis, int N){
    int i = blockIdx.x*blockDim.x + threadIdx.x;
    if(i < N){ float d = (float)cr[i] + 1.0f; deg[i] = d; dis[i] = rsqrtf(d); }
}

// ---------------- LDS-tiled bf16 MFMA GEMM ----------------
template<int OUT>
__global__ __launch_bounds__(256) void gemm_lds(
    const unsigned short* __restrict__ A, const unsigned short* __restrict__ Bt,
    const float* __restrict__ bias, void* __restrict__ Cout,
    int M, int K, int Nc)
{
    __shared__ unsigned short As[128*64];
    __shared__ unsigned short Bs[128*64];
    int tid = threadIdx.x;
    int lane = tid & 63;
    int wid = tid >> 6;
    int bm = blockIdx.y*128, bn = blockIdx.x*128;
    int wr = (wid >> 1)*64, wc = (wid & 1)*64;
    int lr = lane & 15, kg = lane >> 4;
    f32x4 acc[4][4];
    #pragma unroll
    for(int i = 0; i < 4; i++)
        #pragma unroll
        for(int j = 0; j < 4; j++) acc[i][j] = (f32x4){0.f,0.f,0.f,0.f};

    for(int k0 = 0; k0 < K; k0 += 64){
        #pragma unroll
        for(int i = 0; i < 4; i++){
            int q = tid + 256*i;
            int row = q >> 3, c8 = (q & 7)*8;
            int ar = bm + row; if(ar >= M) ar = M - 1;
            *(short8v*)&As[row*64 + c8] = *(const short8v*)&A[(size_t)ar*K + k0 + c8];
            *(short8v*)&Bs[row*64 + c8] = *(const short8v*)&Bt[(size_t)(bn + row)*K + k0 + c8];
        }
        __syncthreads();
        #pragma unroll
        for(int kk = 0; kk < 2; kk++){
            short8v a[4], b[4];
            #pragma unroll
            for(int i = 0; i < 4; i++)
                a[i] = *(const short8v*)&As[(wr + i*16 + lr)*64 + kk*32 + kg*8];
            #pragma unroll
            for(int j = 0; j < 4; j++)
                b[j] = *(const short8v*)&Bs[(wc + j*16 + lr)*64 + kk*32 + kg*8];
            #pragma unroll
            for(int i = 0; i < 4; i++)
                #pragma unroll
                for(int j = 0; j < 4; j++)
                    acc[i][j] = __builtin_amdgcn_mfma_f32_16x16x32_bf16(a[i], b[j], acc[i][j], 0, 0, 0);
        }
        __syncthreads();
    }
    #pragma unroll
    for(int j = 0; j < 4; j++){
        int col = bn + wc + j*16 + lr;
        float bs = bias ? bias[col] : 0.f;
        #pragma unroll
        for(int i = 0; i < 4; i++){
            int rbase = bm + wr + i*16 + kg*4;
            #pragma unroll
            for(int r = 0; r < 4; r++){
                int rw = rbase + r;
                if(rw < M){
                    float val = acc[i][j][r] + bs;
                    if(OUT == 1)
                        ((unsigned short*)Cout)[(size_t)rw*Nc + col] = f2bf(val);
                    else if(OUT == 2)
                        ((_Float16*)Cout)[(size_t)rw*Nc + col] = (_Float16)val;
                    else
                        ((float*)Cout)[(size_t)rw*Nc + col] = val;
                }
            }
        }
    }
}

// ---------------- GCN gather v11: wave-per-node, LDS-staged weights, chunk-4, f16 dot2 ----------------
__device__ __forceinline__ void edge_acc5(
    uint4 ea0, uint4 ea1, unsigned hu, float nm,
    const unsigned* __restrict__ w0, const unsigned* __restrict__ w1,
    float be0, float be1, float& a0, float& a1)
{
    float ev0 = be0, ev1 = be1;
    unsigned ea[8] = {ea0.x, ea0.y, ea0.z, ea0.w, ea1.x, ea1.y, ea1.z, ea1.w};
    #pragma unroll
    for(int kk = 0; kk < 8; kk++){
        ev0 = __builtin_amdgcn_fdot2(ash2(ea[kk]), ash2(w0[kk]), ev0, false);
        ev1 = __builtin_amdgcn_fdot2(ash2(ea[kk]), ash2(w1[kk]), ev1, false);
    }
    float sx = fmaxf(asf(hu << 16) + ev0, 0.f);
    float sy = fmaxf(asf(hu & 0xffff0000u) + ev1, 0.f);
    a0 += nm*sx; a1 += nm*sy;
}

__global__ __launch_bounds__(256) void gcn_gather_v11(
    const unsigned* __restrict__ hlin, const int* __restrict__ curg,
    const int2* __restrict__ gslot, const unsigned* __restrict__ eattrh,
    const float* __restrict__ dis, const unsigned* __restrict__ wpk_l,
    const float* __restrict__ be, const float* __restrict__ root,
    const float* __restrict__ deg,
    unsigned* __restrict__ xc, unsigned* __restrict__ hcur, int blk, int N)
{
    __shared__ unsigned sw[1024];   // 4 KB: this layer's packed We pairs [8][128]
    int tid = threadIdx.x;
    int lane = tid & 63;
    *(uint4*)&sw[tid*4] = *(const uint4*)&wpk_l[tid*4];
    __syncthreads();
    int node = __builtin_amdgcn_readfirstlane((int)(blockIdx.x*4 + (tid >> 6)));
    if(node >= N) return;
    unsigned w0[8], w1[8];
    #pragma unroll
    for(int kk = 0; kk < 8; kk++){
        w0[kk] = sw[kk*128 + 2*lane];
        w1[kk] = sw[kk*128 + 2*lane + 1];
    }
    f32x2 be2 = ((const f32x2*)be)[lane];
    f32x2 rt2 = ((const f32x2*)root)[lane];
    float disn = dis[node];
    int s0 = node*GCAP;
    int s1 = s0 + min(curg[node], GCAP);
    float a0 = 0.f, a1 = 0.f;
    int s = s0;
    for(; s + 4 <= s1; s += 4){
        int2 sl0 = gslot[s+0], sl1 = gslot[s+1], sl2 = gslot[s+2], sl3 = gslot[s+3];
        float d0 = dis[sl0.x], d1 = dis[sl1.x], d2 = dis[sl2.x], d3 = dis[sl3.x];
        unsigned h0 = hlin[(size_t)sl0.x*64 + lane];
        unsigned h1 = hlin[(size_t)sl1.x*64 + lane];
        unsigned h2 = hlin[(size_t)sl2.x*64 + lane];
        unsigned h3 = hlin[(size_t)sl3.x*64 + lane];
        uint4 e00 = *(const uint4*)(eattrh + (size_t)sl0.y*8);
        uint4 e01 = *(const uint4*)(eattrh + (size_t)sl0.y*8 + 4);
        uint4 e10 = *(const uint4*)(eattrh + (size_t)sl1.y*8);
        uint4 e11 = *(const uint4*)(eattrh + (size_t)sl1.y*8 + 4);
        uint4 e20 = *(const uint4*)(eattrh + (size_t)sl2.y*8);
        uint4 e21 = *(const uint4*)(eattrh + (size_t)sl2.y*8 + 4);
        uint4 e30 = *(const uint4*)(eattrh + (size_t)sl3.y*8);
        uint4 e31 = *(const uint4*)(eattrh + (size_t)sl3.y*8 + 4);
        edge_acc5(e00, e01, h0, d0*disn, w0, w1, be2.x, be2.y, a0, a1);
        edge_acc5(e10, e11, h1, d1*disn, w0, w1, be2.x, be2.y, a0, a1);
        edge_acc5(e20, e21, h2, d2*disn, w0, w1, be2.x, be2.y, a0, a1);
        edge_acc5(e30, e31, h3, d3*disn, w0, w1, be2.x, be2.y, a0, a1);
    }
    for(; s < s1; s++){
        int2 sl0 = gslot[s];
        float d0 = dis[sl0.x];
        unsigned h0 = hlin[(size_t)sl0.x*64 + lane];
        uint4 e00 = *(const uint4*)(eattrh + (size_t)sl0.y*8);
        uint4 e01 = *(const uint4*)(eattrh + (size_t)sl0.y*8 + 4);
        edge_acc5(e00, e01, h0, d0*disn, w0, w1, be2.x, be2.y, a0, a1);
    }
    unsigned hlu = hlin[(size_t)node*64 + lane];
    float hlx = asf(hlu << 16), hly = asf(hlu & 0xffff0000u);
    float dinv = 1.f/deg[node];
    float v0 = fmaxf(a0 + fmaxf(hlx + rt2.x, 0.f)*dinv, 0.f);
    float v1 = fmaxf(a1 + fmaxf(hly + rt2.y, 0.f)*dinv, 0.f);
    unsigned p = packbf(v0, v1);
    hcur[(size_t)node*64 + lane] = p;
    xc[(size_t)node*256 + (size_t)blk*64 + lane] = p;
}

// ---------------- BN statistics from bf16 xc ----------------
__global__ __launch_bounds__(256) void bn_stats_bf(
    const unsigned* __restrict__ xc, int N, float* __restrict__ stats)
{
    int c0 = threadIdx.x;
    int rows_per = (N + gridDim.x - 1)/gridDim.x;
    int r0 = blockIdx.x*rows_per, r1 = min(N, r0 + rows_per);
    float s0=0, q0=0, s1=0, q1=0;
    for(int r = r0; r < r1; r++){
        unsigned u = xc[(size_t)r*256 + c0];
        float a = asf(u << 16), b = asf(u & 0xffff0000u);
        s0 += a; q0 += a*a; s1 += b; q1 += b*b;
    }
    atomicAdd(&stats[2*c0+0], s0);  atomicAdd(&stats[512 + 2*c0+0], q0);
    atomicAdd(&stats[2*c0+1], s1);  atomicAdd(&stats[512 + 2*c0+1], q1);
}

// ---------------- fold: blocks [0,256) -> Wqkft row j; block 256 -> bqkf ----------------
__global__ void fold_all(const float* __restrict__ gamma, const float* __restrict__ beta,
                         const float* __restrict__ stats, float Ninv,
                         const float* __restrict__ WseWqk, const float* __restrict__ bconst,
                         unsigned short* __restrict__ Wqkft, float* __restrict__ bqkf)
{
    int b = blockIdx.x, t = threadIdx.x;
    if(b < 256){
        int j = b;
        #pragma unroll
        for(int half = 0; half < 2; half++){
            int k = t + half*256;
            float mu  = stats[k]*Ninv;
            float var = stats[512+k]*Ninv - mu*mu;
            float sc  = gamma[k]*rsqrtf(var + 1e-5f);
            Wqkft[(size_t)j*512 + k] = f2bf(sc * WseWqk[(size_t)k*256 + j]);
        }
    } else {
        int j = t;
        float acc = bconst[j];
        for(int k = 0; k < 512; k++){
            float mu  = stats[k]*Ninv;
            float var = stats[512+k]*Ninv - mu*mu;
            float sc  = gamma[k]*rsqrtf(var + 1e-5f);
            float sh  = beta[k] - mu*sc;
            acc += sh*WseWqk[(size_t)k*256 + j];
        }
        bqkf[j] = acc;
    }
}

// ---------------- fused attention v8: slot buckets, f16 dot2, chunk-max softmax ----------------
__global__ __launch_bounds__(256) void attn_fused_v8(
    const unsigned* __restrict__ qk, const unsigned* __restrict__ v,
    const int* __restrict__ curd, const int* __restrict__ asrcS,
    unsigned* __restrict__ out, int N)
{
    int lane = threadIdx.x & 63;
    int node = __builtin_amdgcn_readfirstlane((int)((blockIdx.x*blockDim.x + threadIdx.x) >> 6));
    if(node >= N) return;
    int cnt = min(curd[node], GCAP);
    int s0 = node*GCAP, s1 = s0 + cnt;
    float o0 = 0.f, o1 = 0.f;
    if(cnt > 0){
        h16x2 qi2 = ash2(qk[(size_t)node*128 + 64 + lane]);
        float m = -INFINITY, ssum = 0.f, a0 = 0.f, a1 = 0.f;
        int s = s0;
        for(; s + 4 <= s1; s += 4){
            int sr0 = asrcS[s+0], sr1 = asrcS[s+1], sr2 = asrcS[s+2], sr3 = asrcS[s+3];
            unsigned qj[4], vv[4];
            qj[0] = qk[(size_t)sr0*128 + lane];  vv[0] = v[(size_t)sr0*64 + lane];
            qj[1] = qk[(size_t)sr1*128 + lane];  vv[1] = v[(size_t)sr1*64 + lane];
            qj[2] = qk[(size_t)sr2*128 + lane];  vv[2] = v[(size_t)sr2*64 + lane];
            qj[3] = qk[(size_t)sr3*128 + lane];  vv[3] = v[(size_t)sr3*64 + lane];
            float l[4];
            #pragma unroll
            for(int j = 0; j < 4; j++){
                float p = __builtin_amdgcn_fdot2(qi2, ash2(qj[j]), 0.f, false);
                p += __shfl_xor(p, 1);
                p += __shfl_xor(p, 2);
                p += __shfl_xor(p, 4);
                l[j] = p*0.25f;
            }
            float mc = fmaxf(fmaxf(fmaxf(l[0], l[1]), fmaxf(l[2], l[3])), m);
            float sc = __expf(m - mc);
            float p0 = __expf(l[0] - mc), p1 = __expf(l[1] - mc);
            float p2 = __expf(l[2] - mc), p3 = __expf(l[3] - mc);
            h16x2 v0 = ash2(vv[0]), v1 = ash2(vv[1]), v2 = ash2(vv[2]), v3 = ash2(vv[3]);
            ssum = ssum*sc + (p0 + p1 + p2 + p3);
            a0 = a0*sc + p0*(float)v0.x + p1*(float)v1.x + p2*(float)v2.x + p3*(float)v3.x;
            a1 = a1*sc + p0*(float)v0.y + p1*(float)v1.y + p2*(float)v2.y + p3*(float)v3.y;
            m = mc;
        }
        for(; s < s1; s++){
            int srx = asrcS[s];
            h16x2 qj2 = ash2(qk[(size_t)srx*128 + lane]);
            h16x2 v2  = ash2(v [(size_t)srx*64  + lane]);
            float p = __builtin_amdgcn_fdot2(qi2, qj2, 0.f, false);
            p += __shfl_xor(p, 1);
            p += __shfl_xor(p, 2);
            p += __shfl_xor(p, 4);
            float l = p*0.25f;
            float mn = fmaxf(m, l);
            float sc = __expf(m - mn);
            float pe = __expf(l - mn);
            ssum = ssum*sc + pe;
            a0 = a0*sc + pe*(float)v2.x;
            a1 = a1*sc + pe*(float)v2.y;
            m = mn;
        }
        float inv = 1.f/ssum;
        o0 = a0*inv; o1 = a1*inv;
    }
    out[(size_t)node*64 + lane] = packbf(o0, o1);
}

extern "C" void kernel_launch(void* const* d_in, const int* in_sizes, int n_in,
                              void* d_out, int out_size, void* d_ws, size_t ws_size,
                              hipStream_t stream)
{
    const float* x     = (const float*)d_in[0];
    const int*   ei    = (const int*)  d_in[1];
    const float* eattr = (const float*)d_in[2];
    const int*   dei   = (const int*)  d_in[3];
    const float* Wv    = (const float*)d_in[4];
    const float* Wqk   = (const float*)d_in[5];
    const float* gW    = (const float*)d_in[6];
    const float* gb    = (const float*)d_in[7];
    const float* groot = (const float*)d_in[8];
    const float* gWe   = (const float*)d_in[9];
    const float* gbe   = (const float*)d_in[10];
    const float* gamma = (const float*)d_in[11];
    const float* beta  = (const float*)d_in[12];
    const float* Wse   = (const float*)d_in[13];
    const float* bse   = (const float*)d_in[14];
    const float* Wout  = (const float*)d_in[15];
    const float* bout  = (const float*)d_in[16];

    const int N = in_sizes[0]/D;
    const int E = in_sizes[1]/2;
    const int L = in_sizes[7]/D;

    float* ws = (float*)d_ws;
    size_t o = 0;
    auto alloc = [&](size_t n){ size_t r = o; o += (n + 63) & ~(size_t)63; return r; };
    size_t f_deg   = alloc((size_t)N);
    size_t f_dis   = alloc((size_t)N);
    size_t f_hlin  = alloc((size_t)N*64);
    size_t f_hcur  = alloc((size_t)N*64);
    size_t f_xbf   = alloc((size_t)N*64);
    size_t f_xc    = alloc((size_t)N*256);
    size_t f_st    = alloc(1024);
    size_t f_cnt   = alloc((size_t)N*3);
    size_t f_gslot = alloc((size_t)N*GCAP*2);
    size_t f_asrc  = alloc((size_t)N*GCAP);
    size_t f_eah   = alloc((size_t)E*8);
    size_t f_wgt   = alloc(40960 + 64);
    size_t f_wpk   = alloc(3*1024);
    size_t f_wsq   = alloc(512*256);
    size_t f_bcn   = alloc(256);
    size_t f_wqf   = alloc(65536);
    size_t f_bqf   = alloc(256);
    size_t f_qk    = alloc((size_t)N*128);
    size_t f_vb    = alloc((size_t)N*64);
    size_t f_aout  = alloc((size_t)N*64);
    (void)ws_size;

    float* deg  = ws + f_deg;   float* dis  = ws + f_dis;
    unsigned* hlin = (unsigned*)(ws + f_hlin);
    unsigned* hcur = (unsigned*)(ws + f_hcur);
    unsigned* xbf  = (unsigned*)(ws + f_xbf);
    unsigned* xc   = (unsigned*)(ws + f_xc);
    float* stats = ws + f_st;
    int* cnts = (int*)(ws + f_cnt);
    int* cr = cnts, *curg = cnts + N, *curd = cnts + 2*N;
    int2* gslot = (int2*)(ws + f_gslot);
    int* asrcS = (int*)(ws + f_asrc);
    unsigned* eattrh = (unsigned*)(ws + f_eah);
    unsigned short* wbase = (unsigned short*)(ws + f_wgt);
    unsigned short* gWt   = wbase;
    unsigned short* Wvt   = gWt + 3*128*128;
    unsigned short* Woutt = Wvt + 128*128;
    unsigned* wpk = (unsigned*)(ws + f_wpk);
    float* WseWqk = ws + f_wsq;
    float* bconst = ws + f_bcn;
    unsigned short* Wqkft = (unsigned short*)(ws + f_wqf);
    float* bqkf = ws + f_bqf;
    unsigned* qk   = (unsigned*)(ws + f_qk);
    unsigned* vbuf = (unsigned*)(ws + f_vb);
    unsigned* aout = (unsigned*)(ws + f_aout);

    const int* e_row = ei;        const int* e_col = ei + E;
    const int* a_src = dei;       const int* a_dst = dei + E;

    dim3 blk256(256);
    int gE = (E+255)/256, gN = (N+255)/256;
    int gNode = ((size_t)N*64 + 255)/256;
    int gX = gNode;
    int gM128 = (N+127)/128;

    // ---- fused prep ----
    hipMemsetAsync(cnts, 0, (size_t)N*3*sizeof(int), stream);
    prep_all<<<gE + gX + 1177, blk256, 0, stream>>>(
        e_row, e_col, a_src, a_dst, E, N, gE, gX, L,
        eattr, x, gW, Wv, Wqk, Wout, gWe, bse, Wse,
        cr, curg, curd, gslot, asrcS, eattrh,
        xbf, xc, gWt, Wvt, Woutt, wpk, WseWqk, bconst);
    deg_fin2<<<gN, blk256, 0, stream>>>(cr, deg, dis, N);

    // ---- GCN layers ----
    const unsigned* hin = xbf;
    for(int l = 0; l < L; l++){
        dim3 g(1, gM128);
        gemm_lds<1><<<g, blk256, 0, stream>>>((const unsigned short*)hin, gWt + (size_t)l*D*D,
                                              gb + (size_t)l*D, hlin, N, 128, 128);
        gcn_gather_v11<<<gNode, blk256, 0, stream>>>(hlin, curg, gslot, eattrh, dis,
                                                     wpk + (size_t)l*1024, gbe + (size_t)l*D,
                                                     groot + (size_t)l*D, deg, xc, hcur, l+1, N);
        hin = hcur;
    }

    // ---- BN stats + fold ----
    hipMemsetAsync(stats, 0, 1024*sizeof(float), stream);
    bn_stats_bf<<<1024, blk256, 0, stream>>>(xc, N, stats);
    float Ninv = 1.0f/(float)N;
    fold_all<<<257, blk256, 0, stream>>>(gamma, beta, stats, Ninv, WseWqk, bconst, Wqkft, bqkf);

    // ---- projections ----
    {   dim3 g(1, gM128);   // v = x @ Wv (f16 out)
        gemm_lds<2><<<g, blk256, 0, stream>>>((const unsigned short*)xbf, Wvt, nullptr, vbuf, N, 128, 128);
    }
    {   dim3 g(2, gM128);   // qk = xc @ Wqkft + bqkf (f16 out), K=512
        gemm_lds<2><<<g, blk256, 0, stream>>>((const unsigned short*)xc, Wqkft, bqkf, qk, N, 512, 256);
    }

    // ---- fused attention ----
    attn_fused_v8<<<gNode, blk256, 0, stream>>>(qk, vbuf, curd, asrcS, aout, N);

    // ---- out = attn_out @ Wout + bout (fp32 out) ----
    {   dim3 g(1, gM128);
        gemm_lds<0><<<g, blk256, 0, stream>>>((const unsigned short*)aout, Woutt, bout, (float*)d_out, N, 128, 128);
    }
}